// Round 1
// baseline (421.552 us; speedup 1.0000x reference)
//
#include <hip/hip_runtime.h>
#include <math.h>

#define R_ 2048
#define A_ 16384
#define E_ 131072
#define K_ 48
#define NREL_ 7

// ---------------------------------------------------------------- res_feat
__global__ __launch_bounds__(256) void k_resfeat(
    const float* __restrict__ node, const float* __restrict__ Wres,
    const float* __restrict__ bres, float* __restrict__ resfeat,
    float* __restrict__ bufA)
{
    int idx = blockIdx.x * 256 + threadIdx.x;
    int r = idx >> 6, c = idx & 63;
    float s = bres[c];
#pragma unroll
    for (int i = 0; i < 21; ++i) s += node[r * 21 + i] * Wres[i * 64 + c];
    resfeat[r * 64 + c] = s;
    bufA[(size_t)r * 512 + 448 + c] = s;   // concat [agg | res_feat] layout
}

// ---------------------------------------------------------------- edge scatter (atomic)
__global__ __launch_bounds__(256) void k_edges(
    const int* __restrict__ esrc, const int* __restrict__ edst,
    const int* __restrict__ erel, const float* __restrict__ resfeat,
    float* __restrict__ bufA)
{
    int idx = blockIdx.x * 256 + threadIdx.x;
    int e = idx >> 6, c = idx & 63;
    int d = edst[e], rel = erel[e], s = esrc[e];
    atomicAdd(&bufA[(size_t)d * 512 + rel * 64 + c], resfeat[s * 64 + c]);
}

// ---------------------------------------------------------------- ball query (exact top-K=48 by (d, idx))
__global__ __launch_bounds__(256) void k_ball(
    const float* __restrict__ pos, const int* __restrict__ ca_idx,
    int* __restrict__ nbr)
{
    __shared__ float ds[A_];            // 64 KB
    __shared__ unsigned hist[256];
    __shared__ unsigned hist2[256];
    __shared__ int sc[256];
    __shared__ float candd[128];
    __shared__ int candi[128];
    __shared__ unsigned s_cnt, s_ccnt;
    __shared__ int s_list[K_];
    __shared__ int sB, sNeed, sB2, sNeed2, sTotal;

    int tid = threadIdx.x;
    int r = blockIdx.x;
    int ca = ca_idx[r];
    float cx = pos[ca * 3 + 0], cy = pos[ca * 3 + 1], cz = pos[ca * 3 + 2];

    hist[tid] = 0u;
    if (tid == 0) { s_cnt = 0u; s_ccnt = 0u; }
    __syncthreads();

    for (int a = tid; a < A_; a += 256) {
        float dx = pos[a * 3 + 0] - cx;
        float dy = pos[a * 3 + 1] - cy;
        float dz = pos[a * 3 + 2] - cz;
        float d2 = dx * dx + dy * dy + dz * dz;
        float d = sqrtf(d2 + 1e-12f);
        ds[a] = d;
        if (d < 10.0f) {
            int b = (int)(d * 25.6f); if (b > 255) b = 255;
            atomicAdd(&hist[b], 1u);
        }
    }
    __syncthreads();

    // inclusive scan of hist
    sc[tid] = (int)hist[tid];
    __syncthreads();
    for (int s = 1; s < 256; s <<= 1) {
        int v = (tid >= s) ? sc[tid - s] : 0;
        __syncthreads();
        sc[tid] += v;
        __syncthreads();
    }
    if (tid == 0) sTotal = sc[255];
    if (sc[tid] >= K_ && (tid == 0 || sc[tid - 1] < K_)) {
        sB = tid;
        sNeed = K_ - (sc[tid] - (int)hist[tid]);
    }
    __syncthreads();

    int mode;
    if (sTotal <= K_) mode = 0;
    else mode = ((int)hist[sB] > 128) ? 2 : 1;

    if (mode == 0) {
        for (int a = tid; a < A_; a += 256)
            if (ds[a] < 10.0f) { unsigned p = atomicAdd(&s_cnt, 1u); s_list[p] = a; }
    } else if (mode == 1) {
        int B = sB;
        for (int a = tid; a < A_; a += 256) {
            float d = ds[a];
            if (d < 10.0f) {
                int b = (int)(d * 25.6f); if (b > 255) b = 255;
                if (b < B) { unsigned p = atomicAdd(&s_cnt, 1u); s_list[p] = a; }
                else if (b == B) { unsigned c = atomicAdd(&s_ccnt, 1u); if (c < 128u) { candd[c] = d; candi[c] = a; } }
            }
        }
    }
    // mode 2: refine boundary bin with a monotone sub-key
    if (mode == 2) {
        int B = sB;
        float lo = B * 0.0390625f;
        hist2[tid] = 0u;
        __syncthreads();
        for (int a = tid; a < A_; a += 256) {
            float d = ds[a];
            if (d < 10.0f) {
                int b = (int)(d * 25.6f); if (b > 255) b = 255;
                if (b == B) {
                    int k2 = (int)((d - lo) * 6553.6f);
                    if (k2 < 0) k2 = 0; if (k2 > 255) k2 = 255;
                    atomicAdd(&hist2[k2], 1u);
                }
            }
        }
        __syncthreads();
        sc[tid] = (int)hist2[tid];
        __syncthreads();
        for (int s = 1; s < 256; s <<= 1) {
            int v = (tid >= s) ? sc[tid - s] : 0;
            __syncthreads();
            sc[tid] += v;
            __syncthreads();
        }
        if (sc[tid] >= sNeed && (tid == 0 || sc[tid - 1] < sNeed)) {
            sB2 = tid;
            sNeed2 = sNeed - (sc[tid] - (int)hist2[tid]);
        }
        __syncthreads();
        int B2 = sB2;
        for (int a = tid; a < A_; a += 256) {
            float d = ds[a];
            if (d < 10.0f) {
                int b = (int)(d * 25.6f); if (b > 255) b = 255;
                if (b < B) { unsigned p = atomicAdd(&s_cnt, 1u); s_list[p] = a; }
                else if (b == B) {
                    int k2 = (int)((d - lo) * 6553.6f);
                    if (k2 < 0) k2 = 0; if (k2 > 255) k2 = 255;
                    if (k2 < B2) { unsigned p = atomicAdd(&s_cnt, 1u); s_list[p] = a; }
                    else if (k2 == B2) { unsigned c = atomicAdd(&s_ccnt, 1u); if (c < 128u) { candd[c] = d; candi[c] = a; } }
                }
            }
        }
    }
    __syncthreads();

    int needN = (mode == 0) ? 0 : ((mode == 1) ? sNeed : sNeed2);
    unsigned C = s_ccnt; if (C > 128u) C = 128u;
    if (tid < (int)C) {
        float di = candd[tid]; int ii = candi[tid];
        int rank = 0;
        for (unsigned j = 0; j < C; ++j) {
            float dj = candd[j]; int ij = candi[j];
            if (dj < di || (dj == di && ij < ii)) ++rank;
        }
        if (rank < needN) { unsigned p = atomicAdd(&s_cnt, 1u); s_list[p] = ii; }
    }
    __syncthreads();
    if (tid < K_) nbr[r * K_ + tid] = (tid < (int)s_cnt) ? s_list[tid] : -1;
}

// ---------------------------------------------------------------- env: point-MLP + masked maxpool + env@W2
__global__ __launch_bounds__(256) void k_env(
    const float* __restrict__ pos, const int* __restrict__ atom_name,
    const int* __restrict__ ca_idx, const int* __restrict__ nbr,
    const float* __restrict__ emb, const float* __restrict__ Wxyz,
    const float* __restrict__ W1, const float* __restrict__ b1,
    const float* __restrict__ W2, const float* __restrict__ b2,
    float* __restrict__ outZ1)
{
    __shared__ float W1s[64 * 128];     // 32 KB
    __shared__ float pts[K_ * 64];      // 12 KB
    __shared__ float part[8][128];
    __shared__ float env128[128];
    __shared__ int s_a[K_];
    __shared__ float s_d[K_][3];

    int tid = threadIdx.x, r = blockIdx.x;
    for (int i = tid; i < 64 * 128; i += 256) W1s[i] = W1[i];

    int ca = ca_idx[r];
    float cx = pos[ca * 3 + 0], cy = pos[ca * 3 + 1], cz = pos[ca * 3 + 2];
    if (tid < K_) {
        int a = nbr[r * K_ + tid];
        s_a[tid] = a;
        if (a >= 0) {
            s_d[tid][0] = pos[a * 3 + 0] - cx;
            s_d[tid][1] = pos[a * 3 + 1] - cy;
            s_d[tid][2] = pos[a * 3 + 2] - cz;
        } else {
            s_d[tid][0] = 0.f; s_d[tid][1] = 0.f; s_d[tid][2] = 0.f;
        }
    }
    __syncthreads();

    for (int idx = tid; idx < K_ * 64; idx += 256) {
        int k = idx >> 6, i = idx & 63;
        int a = s_a[k];
        float v = 0.f;
        if (a >= 0) {
            v = emb[atom_name[a] * 64 + i]
              + s_d[k][0] * Wxyz[i] + s_d[k][1] * Wxyz[64 + i] + s_d[k][2] * Wxyz[128 + i];
        }
        pts[idx] = v;
    }
    __syncthreads();

    // 8 k-groups of 6, 32 j-groups of 4
    {
        int kg = tid >> 5;            // 0..7
        int j0 = (tid & 31) << 2;     // 0..124
        float acc[6][4];
#pragma unroll
        for (int t = 0; t < 6; ++t)
#pragma unroll
            for (int u = 0; u < 4; ++u) acc[t][u] = 0.f;

        for (int i = 0; i < 64; ++i) {
            float pv[6];
#pragma unroll
            for (int t = 0; t < 6; ++t) pv[t] = pts[(kg * 6 + t) * 64 + i];
            float4 w = *(const float4*)&W1s[i * 128 + j0];
#pragma unroll
            for (int t = 0; t < 6; ++t) {
                acc[t][0] += pv[t] * w.x;
                acc[t][1] += pv[t] * w.y;
                acc[t][2] += pv[t] * w.z;
                acc[t][3] += pv[t] * w.w;
            }
        }
        float4 b1v = *(const float4*)&b1[j0];
        float m[4] = { -1e9f, -1e9f, -1e9f, -1e9f };
#pragma unroll
        for (int t = 0; t < 6; ++t) {
            if (s_a[kg * 6 + t] >= 0) {
                m[0] = fmaxf(m[0], fmaxf(acc[t][0] + b1v.x, 0.f));
                m[1] = fmaxf(m[1], fmaxf(acc[t][1] + b1v.y, 0.f));
                m[2] = fmaxf(m[2], fmaxf(acc[t][2] + b1v.z, 0.f));
                m[3] = fmaxf(m[3], fmaxf(acc[t][3] + b1v.w, 0.f));
            }
        }
#pragma unroll
        for (int u = 0; u < 4; ++u) part[kg][j0 + u] = m[u];
    }
    __syncthreads();
    if (tid < 128) {
        float m = part[0][tid];
#pragma unroll
        for (int g = 1; g < 8; ++g) m = fmaxf(m, part[g][tid]);
        env128[tid] = m;
    }
    __syncthreads();
    // env256 = relu(env128 @ W2 + b2) -> write into concat buffer at col 512+
    {
        float s = b2[tid];
        for (int i = 0; i < 128; ++i) s += env128[i] * W2[i * 256 + tid];
        outZ1[(size_t)r * 768 + 512 + tid] = fmaxf(s, 0.f);
    }
}

// ---------------------------------------------------------------- BN column stats
__global__ __launch_bounds__(512) void k_stats(
    const float* __restrict__ Z, float* __restrict__ stats)
{
    int j = threadIdx.x;
    int r0 = blockIdx.x * 16;
    float s = 0.f, q = 0.f;
    for (int r = r0; r < r0 + 16; ++r) {
        float v = Z[(size_t)r * 512 + j];
        s += v; q += v * v;
    }
    atomicAdd(&stats[j], s);
    atomicAdd(&stats[512 + j], q);
}

// ---------------------------------------------------------------- generic 64x64 f32 GEMM
template<bool RELU_OUT, bool BSPLIT, bool BN_A>
__global__ __launch_bounds__(256) void k_gemm(
    const float* __restrict__ A, int lda, int K,
    const float* __restrict__ B1, const float* __restrict__ B2, int splitRow,
    const float* __restrict__ bias,
    const float* __restrict__ stats, const float* __restrict__ gamma,
    const float* __restrict__ beta,
    float* __restrict__ C, int ldc)
{
    __shared__ float As[16][68];
    __shared__ float Bs[16][64];
    __shared__ float bnsc[BN_A ? 512 : 1];
    __shared__ float bnsh[BN_A ? 512 : 1];

    int tid = threadIdx.x;
    int m0 = blockIdx.y * 64, n0 = blockIdx.x * 64;

    if (BN_A) {
        for (int i = tid; i < K; i += 256) {
            float mean = stats[i] * (1.0f / 2048.0f);
            float var = stats[512 + i] * (1.0f / 2048.0f) - mean * mean;
            float inv = 1.0f / sqrtf(var + 1e-5f);
            float scv = gamma[i] * inv;
            bnsc[i] = scv;
            bnsh[i] = beta[i] - mean * scv;
        }
        __syncthreads();
    }

    int arow = tid >> 2, akk = (tid & 3) << 2;
    int bk = tid >> 4, bn = (tid & 15) << 2;
    int tx = tid & 15, ty = tid >> 4;
    float acc[4][4] = {};

    for (int k0 = 0; k0 < K; k0 += 16) {
        float4 av = *(const float4*)(A + (size_t)(m0 + arow) * lda + k0 + akk);
        if (BN_A) {
            av.x = fmaxf(av.x * bnsc[k0 + akk + 0] + bnsh[k0 + akk + 0], 0.f);
            av.y = fmaxf(av.y * bnsc[k0 + akk + 1] + bnsh[k0 + akk + 1], 0.f);
            av.z = fmaxf(av.z * bnsc[k0 + akk + 2] + bnsh[k0 + akk + 2], 0.f);
            av.w = fmaxf(av.w * bnsc[k0 + akk + 3] + bnsh[k0 + akk + 3], 0.f);
        }
        int gk = k0 + bk;
        const float* bp;
        if (BSPLIT && gk >= splitRow) bp = B2 + (size_t)(gk - splitRow) * 512 + n0 + bn;
        else                          bp = B1 + (size_t)gk * 512 + n0 + bn;
        float4 bv = *(const float4*)bp;

        __syncthreads();   // previous iteration's reads done
        As[akk + 0][arow] = av.x;
        As[akk + 1][arow] = av.y;
        As[akk + 2][arow] = av.z;
        As[akk + 3][arow] = av.w;
        *(float4*)&Bs[bk][bn] = bv;
        __syncthreads();

#pragma unroll
        for (int kk = 0; kk < 16; ++kk) {
            float4 a = *(const float4*)&As[kk][ty << 2];
            float4 b = *(const float4*)&Bs[kk][tx << 2];
            acc[0][0] += a.x * b.x; acc[0][1] += a.x * b.y; acc[0][2] += a.x * b.z; acc[0][3] += a.x * b.w;
            acc[1][0] += a.y * b.x; acc[1][1] += a.y * b.y; acc[1][2] += a.y * b.z; acc[1][3] += a.y * b.w;
            acc[2][0] += a.z * b.x; acc[2][1] += a.z * b.y; acc[2][2] += a.z * b.z; acc[2][3] += a.z * b.w;
            acc[3][0] += a.w * b.x; acc[3][1] += a.w * b.y; acc[3][2] += a.w * b.z; acc[3][3] += a.w * b.w;
        }
    }

    float4 bb = *(const float4*)(bias + n0 + (tx << 2));
#pragma unroll
    for (int i = 0; i < 4; ++i) {
        float4 o;
        o.x = acc[i][0] + bb.x;
        o.y = acc[i][1] + bb.y;
        o.z = acc[i][2] + bb.z;
        o.w = acc[i][3] + bb.w;
        if (RELU_OUT) {
            o.x = fmaxf(o.x, 0.f); o.y = fmaxf(o.y, 0.f);
            o.z = fmaxf(o.z, 0.f); o.w = fmaxf(o.w, 0.f);
        }
        *(float4*)(C + (size_t)(m0 + (ty << 2) + i) * ldc + n0 + (tx << 2)) = o;
    }
}

// ---------------------------------------------------------------- launch
extern "C" void kernel_launch(void* const* d_in, const int* in_sizes, int n_in,
                              void* d_out, int out_size, void* d_ws, size_t ws_size,
                              hipStream_t stream)
{
    const float* node   = (const float*)d_in[0];
    const float* pos    = (const float*)d_in[1];
    const int*   aname  = (const int*)d_in[2];
    const int*   caidx  = (const int*)d_in[3];
    const int*   esrc   = (const int*)d_in[4];
    const int*   edst   = (const int*)d_in[5];
    const int*   erel   = (const int*)d_in[6];
    const float* emb    = (const float*)d_in[7];
    const float* Wres   = (const float*)d_in[8];
    const float* bres   = (const float*)d_in[9];
    const float* Wxyz   = (const float*)d_in[10];
    const float* W1     = (const float*)d_in[11];
    const float* b1     = (const float*)d_in[12];
    const float* W2     = (const float*)d_in[13];
    const float* b2     = (const float*)d_in[14];
    const float* Wconv  = (const float*)d_in[15];
    const float* bconv  = (const float*)d_in[16];
    const float* Wself  = (const float*)d_in[17];
    const float* We1    = (const float*)d_in[18];
    const float* be1    = (const float*)d_in[19];
    const float* gamma1 = (const float*)d_in[20];
    const float* beta1  = (const float*)d_in[21];
    const float* We2    = (const float*)d_in[22];
    const float* be2    = (const float*)d_in[23];
    float* out = (float*)d_out;

    char* ws = (char*)d_ws;
    float* resfeat = (float*)(ws + 0);                    // R*64
    float* bufA    = (float*)(ws + 524288);               // R*512  (agg | rf)
    float* bufZ1   = (float*)(ws + 524288 + 4194304);     // R*768  (hres | env)
    float* bufZ2   = (float*)(ws + 524288 + 4194304 + 6291456); // R*512 (z pre-BN)
    int*   nbr     = (int*)  (ws + 524288 + 4194304 + 6291456 + 4194304);       // R*48
    float* stats   = (float*)(ws + 524288 + 4194304 + 6291456 + 4194304 + 393216); // 1024

    hipMemsetAsync(bufA, 0, (size_t)R_ * 512 * 4, stream);
    hipMemsetAsync(stats, 0, 1024 * 4, stream);

    k_resfeat<<<R_ * 64 / 256, 256, 0, stream>>>(node, Wres, bres, resfeat, bufA);
    k_ball<<<R_, 256, 0, stream>>>(pos, caidx, nbr);
    k_env<<<R_, 256, 0, stream>>>(pos, aname, caidx, nbr, emb, Wxyz, W1, b1, W2, b2, bufZ1);
    k_edges<<<(size_t)E_ * 64 / 256, 256, 0, stream>>>(esrc, edst, erel, resfeat, bufA);

    dim3 gg(512 / 64, R_ / 64);
    // hres = relu([agg|rf] @ [Wconv;Wself] + bconv) -> bufZ1 cols 0..511
    k_gemm<true, true, false><<<gg, 256, 0, stream>>>(
        bufA, 512, 512, Wconv, Wself, 448, bconv,
        nullptr, nullptr, nullptr, bufZ1, 768);
    // z = [hres|env] @ We1 + be1 -> bufZ2
    k_gemm<false, false, false><<<gg, 256, 0, stream>>>(
        bufZ1, 768, 768, We1, nullptr, 0, be1,
        nullptr, nullptr, nullptr, bufZ2, 512);
    k_stats<<<R_ / 16, 512, 0, stream>>>(bufZ2, stats);
    // out = relu(BN(z)) @ We2 + be2
    k_gemm<false, false, true><<<gg, 256, 0, stream>>>(
        bufZ2, 512, 512, We2, nullptr, 0, be2,
        stats, gamma1, beta1, out, 512);
}

// Round 2
// 273.902 us; speedup vs baseline: 1.5391x; 1.5391x over previous
//
#include <hip/hip_runtime.h>
#include <math.h>

#define R_ 2048
#define A_ 16384
#define E_ 131072
#define K_ 48
#define NREL_ 7

typedef __attribute__((ext_vector_type(8))) short bfrag8;
typedef __attribute__((ext_vector_type(4))) float f32x4v;

__device__ __forceinline__ unsigned short bf16rne(float f) {
    unsigned u = __builtin_bit_cast(unsigned, f);
    u += 0x7FFFu + ((u >> 16) & 1u);
    return (unsigned short)(u >> 16);
}

// ---------------------------------------------------------------- res_feat
__global__ __launch_bounds__(256) void k_resfeat(
    const float* __restrict__ node, const float* __restrict__ Wres,
    const float* __restrict__ bres, float* __restrict__ resfeat,
    float* __restrict__ bufA)
{
    int idx = blockIdx.x * 256 + threadIdx.x;
    int r = idx >> 6, c = idx & 63;
    float s = bres[c];
#pragma unroll
    for (int i = 0; i < 21; ++i) s += node[r * 21 + i] * Wres[i * 64 + c];
    resfeat[r * 64 + c] = s;
    bufA[(size_t)r * 512 + 448 + c] = s;   // concat [agg | res_feat] layout
}

// ---------------------------------------------------------------- weight prep: bf16 transpose [N][K]
__global__ __launch_bounds__(256) void k_prep(
    const float* __restrict__ Wconv, const float* __restrict__ Wself,
    const float* __restrict__ We1, const float* __restrict__ We2,
    unsigned short* __restrict__ Bt1, unsigned short* __restrict__ Bt2,
    unsigned short* __restrict__ Bt3)
{
    int id = blockIdx.x * 256 + threadIdx.x;
    if (id < 262144) {
        int k = id & 511, n = id >> 9;
        float v = (k < 448) ? Wconv[k * 512 + n] : Wself[(k - 448) * 512 + n];
        Bt1[n * 512 + k] = bf16rne(v);
    } else if (id < 655360) {
        int rel = id - 262144;
        int k = rel % 768, n = rel / 768;
        Bt2[n * 768 + k] = bf16rne(We1[k * 512 + n]);
    } else if (id < 917504) {
        int rel = id - 655360;
        int k = rel & 511, n = rel >> 9;
        Bt3[n * 512 + k] = bf16rne(We2[k * 512 + n]);
    }
}

// ---------------------------------------------------------------- edge scatter (atomic)
__global__ __launch_bounds__(256) void k_edges(
    const int* __restrict__ esrc, const int* __restrict__ edst,
    const int* __restrict__ erel, const float* __restrict__ resfeat,
    float* __restrict__ bufA)
{
    int idx = blockIdx.x * 256 + threadIdx.x;
    int e = idx >> 6, c = idx & 63;
    int d = edst[e], rel = erel[e], s = esrc[e];
    atomicAdd(&bufA[(size_t)d * 512 + rel * 64 + c], resfeat[s * 64 + c]);
}

// ---------------------------------------------------------------- ball query (exact top-K=48 by (d, idx)), low-LDS recompute version
__global__ __launch_bounds__(256) void k_ball(
    const float* __restrict__ pos, const int* __restrict__ ca_idx,
    int* __restrict__ nbr)
{
    __shared__ unsigned hist[256];
    __shared__ unsigned hist2[256];
    __shared__ int sc[256];
    __shared__ float candd[128];
    __shared__ int candi[128];
    __shared__ unsigned s_cnt, s_ccnt;
    __shared__ int s_list[64];
    __shared__ int sB, sNeed, sB2, sNeed2, sTotal;

    int tid = threadIdx.x;
    int r = blockIdx.x;
    int ca = ca_idx[r];
    float cx = pos[ca * 3 + 0], cy = pos[ca * 3 + 1], cz = pos[ca * 3 + 2];

    hist[tid] = 0u;
    if (tid == 0) { s_cnt = 0u; s_ccnt = 0u; }
    __syncthreads();

    // ---- pass 1: histogram (4 atoms/lane via 3x float4)
    for (int it = 0; it < 16; ++it) {
        int a0 = it * 1024 + tid * 4;
        const float4* p = (const float4*)(pos + (size_t)a0 * 3);
        float4 p0 = p[0], p1 = p[1], p2 = p[2];
        float xs[4] = { p0.x, p0.w, p1.z, p2.y };
        float ys[4] = { p0.y, p1.x, p1.w, p2.z };
        float zs[4] = { p0.z, p1.y, p2.x, p2.w };
#pragma unroll
        for (int q = 0; q < 4; ++q) {
            float dx = xs[q] - cx, dy = ys[q] - cy, dz = zs[q] - cz;
            float d = sqrtf(dx * dx + dy * dy + dz * dz + 1e-12f);
            if (d < 10.0f) {
                int b = (int)(d * 25.6f); if (b > 255) b = 255;
                atomicAdd(&hist[b], 1u);
            }
        }
    }
    __syncthreads();

    // ---- scan
    sc[tid] = (int)hist[tid];
    __syncthreads();
    for (int s = 1; s < 256; s <<= 1) {
        int v = (tid >= s) ? sc[tid - s] : 0;
        __syncthreads();
        sc[tid] += v;
        __syncthreads();
    }
    if (tid == 0) sTotal = sc[255];
    if (sc[tid] >= K_ && (tid == 0 || sc[tid - 1] < K_)) {
        sB = tid;
        sNeed = K_ - (sc[tid] - (int)hist[tid]);
    }
    __syncthreads();

    int mode = (sTotal <= K_) ? 0 : (((int)hist[sB] > 128) ? 2 : 1);

    // ---- rare: refine boundary bin with sub-histogram (recompute)
    if (mode == 2) {
        int B = sB;
        float lo = B * 0.0390625f;
        hist2[tid] = 0u;
        __syncthreads();
        for (int it = 0; it < 16; ++it) {
            int a0 = it * 1024 + tid * 4;
            const float4* p = (const float4*)(pos + (size_t)a0 * 3);
            float4 p0 = p[0], p1 = p[1], p2 = p[2];
            float xs[4] = { p0.x, p0.w, p1.z, p2.y };
            float ys[4] = { p0.y, p1.x, p1.w, p2.z };
            float zs[4] = { p0.z, p1.y, p2.x, p2.w };
#pragma unroll
            for (int q = 0; q < 4; ++q) {
                float dx = xs[q] - cx, dy = ys[q] - cy, dz = zs[q] - cz;
                float d = sqrtf(dx * dx + dy * dy + dz * dz + 1e-12f);
                if (d < 10.0f) {
                    int b = (int)(d * 25.6f); if (b > 255) b = 255;
                    if (b == B) {
                        int k2 = (int)((d - lo) * 6553.6f);
                        if (k2 < 0) k2 = 0; if (k2 > 255) k2 = 255;
                        atomicAdd(&hist2[k2], 1u);
                    }
                }
            }
        }
        __syncthreads();
        sc[tid] = (int)hist2[tid];
        __syncthreads();
        for (int s = 1; s < 256; s <<= 1) {
            int v = (tid >= s) ? sc[tid - s] : 0;
            __syncthreads();
            sc[tid] += v;
            __syncthreads();
        }
        if (sc[tid] >= sNeed && (tid == 0 || sc[tid - 1] < sNeed)) {
            sB2 = tid;
            sNeed2 = sNeed - (sc[tid] - (int)hist2[tid]);
        }
        __syncthreads();
    }

    // ---- pass 2: selection (recompute)
    {
        int B = (mode == 0) ? 256 : sB;
        float lo = sB * 0.0390625f;
        int B2 = (mode == 2) ? sB2 : 0;
        for (int it = 0; it < 16; ++it) {
            int a0 = it * 1024 + tid * 4;
            const float4* p = (const float4*)(pos + (size_t)a0 * 3);
            float4 p0 = p[0], p1 = p[1], p2 = p[2];
            float xs[4] = { p0.x, p0.w, p1.z, p2.y };
            float ys[4] = { p0.y, p1.x, p1.w, p2.z };
            float zs[4] = { p0.z, p1.y, p2.x, p2.w };
#pragma unroll
            for (int q = 0; q < 4; ++q) {
                int a = a0 + q;
                float dx = xs[q] - cx, dy = ys[q] - cy, dz = zs[q] - cz;
                float d = sqrtf(dx * dx + dy * dy + dz * dz + 1e-12f);
                if (d < 10.0f) {
                    int b = (int)(d * 25.6f); if (b > 255) b = 255;
                    bool take = false, cand = false;
                    if (b < B) take = true;
                    else if (b == B) {
                        if (mode == 1) cand = true;
                        else {
                            int k2 = (int)((d - lo) * 6553.6f);
                            if (k2 < 0) k2 = 0; if (k2 > 255) k2 = 255;
                            if (k2 < B2) take = true;
                            else if (k2 == B2) cand = true;
                        }
                    }
                    if (take) { unsigned pp = atomicAdd(&s_cnt, 1u); s_list[pp] = a; }
                    else if (cand) { unsigned c = atomicAdd(&s_ccnt, 1u); if (c < 128u) { candd[c] = d; candi[c] = a; } }
                }
            }
        }
    }
    __syncthreads();

    int needN = (mode == 0) ? 0 : ((mode == 1) ? sNeed : sNeed2);
    unsigned C = s_ccnt; if (C > 128u) C = 128u;
    if (tid < (int)C) {
        float di = candd[tid]; int ii = candi[tid];
        int rank = 0;
        for (unsigned j = 0; j < C; ++j) {
            float dj = candd[j]; int ij = candi[j];
            if (dj < di || (dj == di && ij < ii)) ++rank;
        }
        if (rank < needN) { unsigned pp = atomicAdd(&s_cnt, 1u); s_list[pp] = ii; }
    }
    __syncthreads();
    if (tid < K_) nbr[r * K_ + tid] = (tid < (int)s_cnt) ? s_list[tid] : -1;
}

// ---------------------------------------------------------------- env: point-MLP + masked maxpool + env@W2
__global__ __launch_bounds__(256) void k_env(
    const float* __restrict__ pos, const int* __restrict__ atom_name,
    const int* __restrict__ ca_idx, const int* __restrict__ nbr,
    const float* __restrict__ emb, const float* __restrict__ Wxyz,
    const float* __restrict__ W1, const float* __restrict__ b1,
    const float* __restrict__ W2, const float* __restrict__ b2,
    float* __restrict__ outZ1)
{
    __shared__ __align__(16) float W1s[64 * 128];     // 32 KB
    __shared__ __align__(16) float pts[K_ * 64];      // 12 KB
    __shared__ float part[8][128];
    __shared__ float env128[128];
    __shared__ int s_a[K_];
    __shared__ float s_d[K_][3];

    int tid = threadIdx.x, r = blockIdx.x;
    for (int i = tid * 4; i < 64 * 128; i += 1024)
        *(float4*)&W1s[i] = *(const float4*)&W1[i];

    int ca = ca_idx[r];
    float cx = pos[ca * 3 + 0], cy = pos[ca * 3 + 1], cz = pos[ca * 3 + 2];
    if (tid < K_) {
        int a = nbr[r * K_ + tid];
        s_a[tid] = a;
        if (a >= 0) {
            s_d[tid][0] = pos[a * 3 + 0] - cx;
            s_d[tid][1] = pos[a * 3 + 1] - cy;
            s_d[tid][2] = pos[a * 3 + 2] - cz;
        } else {
            s_d[tid][0] = 0.f; s_d[tid][1] = 0.f; s_d[tid][2] = 0.f;
        }
    }
    __syncthreads();

    for (int idx = tid; idx < K_ * 64; idx += 256) {
        int k = idx >> 6, i = idx & 63;
        int a = s_a[k];
        float v = 0.f;
        if (a >= 0) {
            v = emb[atom_name[a] * 64 + i]
              + s_d[k][0] * Wxyz[i] + s_d[k][1] * Wxyz[64 + i] + s_d[k][2] * Wxyz[128 + i];
        }
        pts[idx] = v;
    }
    __syncthreads();

    // 8 k-groups of 6, 32 j-groups of 4
    {
        int kg = tid >> 5;            // 0..7
        int j0 = (tid & 31) << 2;     // 0..124
        float acc[6][4];
#pragma unroll
        for (int t = 0; t < 6; ++t)
#pragma unroll
            for (int u = 0; u < 4; ++u) acc[t][u] = 0.f;

        for (int i = 0; i < 64; ++i) {
            float pv[6];
#pragma unroll
            for (int t = 0; t < 6; ++t) pv[t] = pts[(kg * 6 + t) * 64 + i];
            float4 w = *(const float4*)&W1s[i * 128 + j0];
#pragma unroll
            for (int t = 0; t < 6; ++t) {
                acc[t][0] += pv[t] * w.x;
                acc[t][1] += pv[t] * w.y;
                acc[t][2] += pv[t] * w.z;
                acc[t][3] += pv[t] * w.w;
            }
        }
        float4 b1v = *(const float4*)&b1[j0];
        float m[4] = { -1e9f, -1e9f, -1e9f, -1e9f };
#pragma unroll
        for (int t = 0; t < 6; ++t) {
            if (s_a[kg * 6 + t] >= 0) {
                m[0] = fmaxf(m[0], fmaxf(acc[t][0] + b1v.x, 0.f));
                m[1] = fmaxf(m[1], fmaxf(acc[t][1] + b1v.y, 0.f));
                m[2] = fmaxf(m[2], fmaxf(acc[t][2] + b1v.z, 0.f));
                m[3] = fmaxf(m[3], fmaxf(acc[t][3] + b1v.w, 0.f));
            }
        }
#pragma unroll
        for (int u = 0; u < 4; ++u) part[kg][j0 + u] = m[u];
    }
    __syncthreads();
    if (tid < 128) {
        float m = part[0][tid];
#pragma unroll
        for (int g = 1; g < 8; ++g) m = fmaxf(m, part[g][tid]);
        env128[tid] = m;
    }
    __syncthreads();
    // env256 = relu(env128 @ W2 + b2) -> write into concat buffer at col 512+
    {
        float s = b2[tid];
        for (int i = 0; i < 128; ++i) s += env128[i] * W2[i * 256 + tid];
        outZ1[(size_t)r * 768 + 512 + tid] = fmaxf(s, 0.f);
    }
}

// ---------------------------------------------------------------- BN column stats
__global__ __launch_bounds__(512) void k_stats(
    const float* __restrict__ Z, float* __restrict__ stats)
{
    int j = threadIdx.x;
    int r0 = blockIdx.x * 16;
    float s = 0.f, q = 0.f;
    for (int r = r0; r < r0 + 16; ++r) {
        float v = Z[(size_t)r * 512 + j];
        s += v; q += v * v;
    }
    atomicAdd(&stats[j], s);
    atomicAdd(&stats[512 + j], q);
}

// ---------------------------------------------------------------- bf16 MFMA GEMM: C[M,512] = op(A[M,K]) @ Bt^T (+bias)
// BM=32, BN=64, BK=32, 256 threads = 4 waves (2M x 2N), each wave 16x32 output.
template<bool RELU_OUT, bool BN_A>
__global__ __launch_bounds__(256) void k_mgemm(
    const float* __restrict__ A, int lda, int K,
    const unsigned short* __restrict__ Bt,   // [512][K] bf16, row = output col
    const float* __restrict__ bias,
    const float* __restrict__ stats, const float* __restrict__ gamma,
    const float* __restrict__ beta,
    float* __restrict__ C, int ldc)
{
    __shared__ __align__(16) unsigned short As[32 * 32];  // [row][k], XOR-swizzled 16B slots
    __shared__ __align__(16) unsigned short Bs[64 * 32];  // [col][k], XOR-swizzled
    __shared__ float bnsc[BN_A ? 512 : 1];
    __shared__ float bnsh[BN_A ? 512 : 1];

    int tid = threadIdx.x;
    int m0 = blockIdx.y * 32, n0 = blockIdx.x * 64;

    if (BN_A) {
        for (int i = tid; i < 512; i += 256) {
            float mean = stats[i] * (1.0f / 2048.0f);
            float var = stats[512 + i] * (1.0f / 2048.0f) - mean * mean;
            float inv = 1.0f / sqrtf(var + 1e-5f);
            float scv = gamma[i] * inv;
            bnsc[i] = scv;
            bnsh[i] = beta[i] - mean * scv;
        }
        __syncthreads();
    }

    int w = tid >> 6, l = tid & 63;
    int wm = w >> 1, wn = w & 1;

    // staging assignments
    int ar = tid >> 3, ac = tid & 7;        // A: row 0..31, 4-col group 0..7
    int aslot = ac >> 1, ahalf = ac & 1;
    int abyte = ar * 64 + ((aslot ^ ((ar >> 1) & 3)) << 4) + ahalf * 8;
    int bn_ = tid >> 2, bs_ = tid & 3;      // B: col 0..63, 8-k slot 0..3
    int bbyte = bn_ * 64 + ((bs_ ^ ((bn_ >> 1) & 3)) << 4);

    // fragment read offsets
    int fr = l & 15, fo = l >> 4;           // row/col within 16, k-octet
    int arow = 16 * wm + fr;
    int afbyte = arow * 64 + ((fo ^ ((arow >> 1) & 3)) << 4);
    int bcol0 = 32 * wn + fr;
    int bfbyte0 = bcol0 * 64 + ((fo ^ ((bcol0 >> 1) & 3)) << 4);
    int bcol1 = bcol0 + 16;
    int bfbyte1 = bcol1 * 64 + ((fo ^ ((bcol1 >> 1) & 3)) << 4);

    f32x4v acc0 = { 0.f, 0.f, 0.f, 0.f };
    f32x4v acc1 = { 0.f, 0.f, 0.f, 0.f };

    for (int k0 = 0; k0 < K; k0 += 32) {
        float4 av = *(const float4*)(A + (size_t)(m0 + ar) * lda + k0 + ac * 4);
        uint4 bv = *(const uint4*)(Bt + (size_t)(n0 + bn_) * K + k0 + bs_ * 8);
        if (BN_A) {
            int kb = k0 + ac * 4;
            av.x = fmaxf(av.x * bnsc[kb + 0] + bnsh[kb + 0], 0.f);
            av.y = fmaxf(av.y * bnsc[kb + 1] + bnsh[kb + 1], 0.f);
            av.z = fmaxf(av.z * bnsc[kb + 2] + bnsh[kb + 2], 0.f);
            av.w = fmaxf(av.w * bnsc[kb + 3] + bnsh[kb + 3], 0.f);
        }
        unsigned lo = (unsigned)bf16rne(av.x) | ((unsigned)bf16rne(av.y) << 16);
        unsigned hi = (unsigned)bf16rne(av.z) | ((unsigned)bf16rne(av.w) << 16);
        __syncthreads();   // previous iteration's frag reads done
        *(uint2*)((char*)As + abyte) = make_uint2(lo, hi);
        *(uint4*)((char*)Bs + bbyte) = bv;
        __syncthreads();

        bfrag8 af = *(const bfrag8*)((const char*)As + afbyte);
        bfrag8 bf0 = *(const bfrag8*)((const char*)Bs + bfbyte0);
        bfrag8 bf1 = *(const bfrag8*)((const char*)Bs + bfbyte1);
        acc0 = __builtin_amdgcn_mfma_f32_16x16x32_bf16(af, bf0, acc0, 0, 0, 0);
        acc1 = __builtin_amdgcn_mfma_f32_16x16x32_bf16(af, bf1, acc1, 0, 0, 0);
    }

    // epilogue: D col = lane&15, row = (lane>>4)*4 + i  [m89-verified]
    int col0 = n0 + 32 * wn + fr;
    int row = m0 + 16 * wm + fo * 4;
    float bb0 = bias[col0], bb1 = bias[col0 + 16];
#pragma unroll
    for (int i = 0; i < 4; ++i) {
        float v0 = acc0[i] + bb0;
        float v1 = acc1[i] + bb1;
        if (RELU_OUT) { v0 = fmaxf(v0, 0.f); v1 = fmaxf(v1, 0.f); }
        C[(size_t)(row + i) * ldc + col0] = v0;
        C[(size_t)(row + i) * ldc + col0 + 16] = v1;
    }
}

// ---------------------------------------------------------------- launch
extern "C" void kernel_launch(void* const* d_in, const int* in_sizes, int n_in,
                              void* d_out, int out_size, void* d_ws, size_t ws_size,
                              hipStream_t stream)
{
    const float* node   = (const float*)d_in[0];
    const float* pos    = (const float*)d_in[1];
    const int*   aname  = (const int*)d_in[2];
    const int*   caidx  = (const int*)d_in[3];
    const int*   esrc   = (const int*)d_in[4];
    const int*   edst   = (const int*)d_in[5];
    const int*   erel   = (const int*)d_in[6];
    const float* emb    = (const float*)d_in[7];
    const float* Wres   = (const float*)d_in[8];
    const float* bres   = (const float*)d_in[9];
    const float* Wxyz   = (const float*)d_in[10];
    const float* W1     = (const float*)d_in[11];
    const float* b1     = (const float*)d_in[12];
    const float* W2     = (const float*)d_in[13];
    const float* b2     = (const float*)d_in[14];
    const float* Wconv  = (const float*)d_in[15];
    const float* bconv  = (const float*)d_in[16];
    const float* Wself  = (const float*)d_in[17];
    const float* We1    = (const float*)d_in[18];
    const float* be1    = (const float*)d_in[19];
    const float* gamma1 = (const float*)d_in[20];
    const float* beta1  = (const float*)d_in[21];
    const float* We2    = (const float*)d_in[22];
    const float* be2    = (const float*)d_in[23];
    float* out = (float*)d_out;

    char* ws = (char*)d_ws;
    float* resfeat = (float*)(ws + 0);                    // R*64 f32          (512KB)
    float* bufA    = (float*)(ws + 524288);               // R*512 f32 agg|rf  (4MB)
    float* bufZ1   = (float*)(ws + 4718592);              // R*768 f32 hres|env (6MB)
    float* bufZ2   = (float*)(ws + 11010048);             // R*512 f32 z       (4MB)
    int*   nbr     = (int*)  (ws + 15204352);             // R*48 int
    float* stats   = (float*)(ws + 15597568);             // 1024 f32
    unsigned short* Bt1 = (unsigned short*)(ws + 15601664); // 512x512 bf16 (512KB)
    unsigned short* Bt2 = (unsigned short*)(ws + 16125952); // 512x768 bf16 (768KB)
    unsigned short* Bt3 = (unsigned short*)(ws + 16912384); // 512x512 bf16 (512KB)

    hipMemsetAsync(bufA, 0, (size_t)R_ * 512 * 4, stream);
    hipMemsetAsync(stats, 0, 1024 * 4, stream);

    k_prep<<<3584, 256, 0, stream>>>(Wconv, Wself, We1, We2, Bt1, Bt2, Bt3);
    k_resfeat<<<R_ * 64 / 256, 256, 0, stream>>>(node, Wres, bres, resfeat, bufA);
    k_ball<<<R_, 256, 0, stream>>>(pos, caidx, nbr);
    k_env<<<R_, 256, 0, stream>>>(pos, aname, caidx, nbr, emb, Wxyz, W1, b1, W2, b2, bufZ1);
    k_edges<<<(size_t)E_ * 64 / 256, 256, 0, stream>>>(esrc, edst, erel, resfeat, bufA);

    dim3 gg(512 / 64, R_ / 32);
    // hres = relu([agg|rf] @ [Wconv;Wself] + bconv) -> bufZ1 cols 0..511
    k_mgemm<true, false><<<gg, 256, 0, stream>>>(
        bufA, 512, 512, Bt1, bconv, nullptr, nullptr, nullptr, bufZ1, 768);
    // z = [hres|env] @ We1 + be1 -> bufZ2
    k_mgemm<false, false><<<gg, 256, 0, stream>>>(
        bufZ1, 768, 768, Bt2, be1, nullptr, nullptr, nullptr, bufZ2, 512);
    k_stats<<<R_ / 16, 512, 0, stream>>>(bufZ2, stats);
    // out = relu(BN(z)) @ We2 + be2
    k_mgemm<false, true><<<gg, 256, 0, stream>>>(
        bufZ2, 512, 512, Bt3, be2, stats, gamma1, beta1, out, 512);
}

// Round 6
// 234.201 us; speedup vs baseline: 1.8000x; 1.1695x over previous
//
#include <hip/hip_runtime.h>
#include <math.h>

#define R_ 2048
#define A_ 16384
#define E_ 131072
#define K_ 48
#define NREL_ 7

typedef __attribute__((ext_vector_type(8))) short bfrag8;
typedef __attribute__((ext_vector_type(4))) float f32x4v;

__device__ __forceinline__ unsigned short bf16rne(float f) {
    unsigned u = __builtin_bit_cast(unsigned, f);
    u += 0x7FFFu + ((u >> 16) & 1u);
    return (unsigned short)(u >> 16);
}

__device__ __forceinline__ float dist2(float x, float y, float z,
                                       float cx, float cy, float cz) {
    float dx = x - cx, dy = y - cy, dz = z - cz;
    return fmaf(dx, dx, fmaf(dy, dy, dz * dz));   // deterministic everywhere
}

// ---------------------------------------------------------------- prep: weights->bf16 + res_feat
__global__ __launch_bounds__(256) void k_prep(
    const float* __restrict__ Wconv, const float* __restrict__ Wself,
    const float* __restrict__ We1, const float* __restrict__ We2,
    const float* __restrict__ W1,
    const float* __restrict__ node, const float* __restrict__ Wres,
    const float* __restrict__ bres,
    unsigned short* __restrict__ Bt1, unsigned short* __restrict__ Bt2,
    unsigned short* __restrict__ Bt3, unsigned short* __restrict__ W1t,
    float* __restrict__ resfeat, float* __restrict__ bufA)
{
    int id = blockIdx.x * 256 + threadIdx.x;
    if (id < 262144) {
        int k = id & 511, n = id >> 9;
        float v = (k < 448) ? Wconv[k * 512 + n] : Wself[(k - 448) * 512 + n];
        Bt1[n * 512 + k] = bf16rne(v);
    } else if (id < 655360) {
        int rel = id - 262144;
        int k = rel % 768, n = rel / 768;
        Bt2[n * 768 + k] = bf16rne(We1[k * 512 + n]);
    } else if (id < 917504) {
        int rel = id - 655360;
        int k = rel & 511, n = rel >> 9;
        Bt3[n * 512 + k] = bf16rne(We2[k * 512 + n]);
    } else if (id < 925696) {
        int rel = id - 917504;
        int k = rel & 63, n = rel >> 6;     // n<128, k<64
        W1t[n * 64 + k] = bf16rne(W1[k * 128 + n]);
    } else if (id < 1056768) {
        int rel = id - 925696;
        int r = rel >> 6, c = rel & 63;
        float s = bres[c];
#pragma unroll
        for (int i = 0; i < 21; ++i) s += node[r * 21 + i] * Wres[i * 64 + c];
        resfeat[r * 64 + c] = s;
        bufA[(size_t)r * 512 + 448 + c] = s;
    }
}

// ---------------------------------------------------------------- edge scatter (atomic)
__global__ __launch_bounds__(256) void k_edges(
    const int* __restrict__ esrc, const int* __restrict__ edst,
    const int* __restrict__ erel, const float* __restrict__ resfeat,
    float* __restrict__ bufA)
{
    int idx = blockIdx.x * 256 + threadIdx.x;
    int e = idx >> 6, c = idx & 63;
    int d = edst[e], rel = erel[e], s = esrc[e];
    atomicAdd(&bufA[(size_t)d * 512 + rel * 64 + c], resfeat[s * 64 + c]);
}

// ---------------------------------------------------------------- ball query: d2-space bins, LDS bin cache
__global__ __launch_bounds__(256) void k_ball(
    const float* __restrict__ pos, const int* __restrict__ ca_idx,
    int* __restrict__ nbr)
{
    __shared__ unsigned binsw[4096];     // 16KB: 8-bit bin per atom
    __shared__ unsigned hist[256];
    __shared__ unsigned hist2[256];
    __shared__ int sc[256];
    __shared__ float candd[128];
    __shared__ int candi[128];
    __shared__ unsigned s_cnt, s_ccnt;
    __shared__ int s_list[64];
    __shared__ int sB, sNeed, sB2, sNeed2, sTotal;

    int tid = threadIdx.x;
    int r = blockIdx.x;
    int ca = ca_idx[r];
    float cx = pos[ca * 3 + 0], cy = pos[ca * 3 + 1], cz = pos[ca * 3 + 2];

    hist[tid] = 0u;
    if (tid == 0) { s_cnt = 0u; s_ccnt = 0u; }
    __syncthreads();

    // ---- pass 1: d2, bin byte -> LDS, histogram
    for (int it = 0; it < 16; ++it) {
        int a0 = it * 1024 + tid * 4;
        const float4* p = (const float4*)(pos + (size_t)a0 * 3);
        float4 p0 = p[0], p1 = p[1], p2 = p[2];
        float xs[4] = { p0.x, p0.w, p1.z, p2.y };
        float ys[4] = { p0.y, p1.x, p1.w, p2.z };
        float zs[4] = { p0.z, p1.y, p2.x, p2.w };
        unsigned pack = 0;
#pragma unroll
        for (int q = 0; q < 4; ++q) {
            float d2 = dist2(xs[q], ys[q], zs[q], cx, cy, cz);
            int b = 255;
            if (d2 < 100.0f) {
                b = (int)(d2 * 2.56f); if (b > 254) b = 254;
                atomicAdd(&hist[b], 1u);
            }
            pack |= (unsigned)b << (q * 8);
        }
        binsw[it * 256 + tid] = pack;
    }
    __syncthreads();

    // ---- scan
    sc[tid] = (int)hist[tid];
    __syncthreads();
    for (int s = 1; s < 256; s <<= 1) {
        int v = (tid >= s) ? sc[tid - s] : 0;
        __syncthreads();
        sc[tid] += v;
        __syncthreads();
    }
    if (tid == 0) sTotal = sc[255];
    if (sc[tid] >= K_ && (tid == 0 || sc[tid - 1] < K_)) {
        sB = tid;
        sNeed = K_ - (sc[tid] - (int)hist[tid]);
    }
    __syncthreads();

    int mode = (sTotal <= K_) ? 0 : (((int)hist[sB] > 128) ? 2 : 1);

    if (mode <= 1) {
        // ---- selection from LDS bins
        int B = (mode == 0) ? 255 : sB;
        for (int it = 0; it < 16; ++it) {
            unsigned pack = binsw[it * 256 + tid];
            int a0 = it * 1024 + tid * 4;
#pragma unroll
            for (int q = 0; q < 4; ++q) {
                int b = (pack >> (q * 8)) & 255;
                if (b < B) { unsigned pp = atomicAdd(&s_cnt, 1u); s_list[pp] = a0 + q; }
                else if (b == B && mode == 1) {
                    unsigned c = atomicAdd(&s_ccnt, 1u);
                    if (c < 128u) candi[c] = a0 + q;
                }
            }
        }
    } else {
        // ---- mode 2: refine boundary bin in d2-subspace (recompute only byte==B atoms)
        int B = sB;
        float lo2 = B * 0.390625f;
        hist2[tid] = 0u;
        __syncthreads();
        for (int it = 0; it < 16; ++it) {
            unsigned pack = binsw[it * 256 + tid];
            int a0 = it * 1024 + tid * 4;
#pragma unroll
            for (int q = 0; q < 4; ++q) {
                if (((pack >> (q * 8)) & 255) == (unsigned)B) {
                    int a = a0 + q;
                    float d2 = dist2(pos[a * 3], pos[a * 3 + 1], pos[a * 3 + 2], cx, cy, cz);
                    int k2 = (int)((d2 - lo2) * 655.36f);
                    if (k2 < 0) k2 = 0; if (k2 > 255) k2 = 255;
                    atomicAdd(&hist2[k2], 1u);
                }
            }
        }
        __syncthreads();
        sc[tid] = (int)hist2[tid];
        __syncthreads();
        for (int s = 1; s < 256; s <<= 1) {
            int v = (tid >= s) ? sc[tid - s] : 0;
            __syncthreads();
            sc[tid] += v;
            __syncthreads();
        }
        if (sc[tid] >= sNeed && (tid == 0 || sc[tid - 1] < sNeed)) {
            sB2 = tid;
            sNeed2 = sNeed - (sc[tid] - (int)hist2[tid]);
        }
        __syncthreads();
        int B2 = sB2;
        for (int it = 0; it < 16; ++it) {
            unsigned pack = binsw[it * 256 + tid];
            int a0 = it * 1024 + tid * 4;
#pragma unroll
            for (int q = 0; q < 4; ++q) {
                int b = (pack >> (q * 8)) & 255;
                if (b < B) { unsigned pp = atomicAdd(&s_cnt, 1u); s_list[pp] = a0 + q; }
                else if (b == B) {
                    int a = a0 + q;
                    float d2 = dist2(pos[a * 3], pos[a * 3 + 1], pos[a * 3 + 2], cx, cy, cz);
                    int k2 = (int)((d2 - lo2) * 655.36f);
                    if (k2 < 0) k2 = 0; if (k2 > 255) k2 = 255;
                    if (k2 < B2) { unsigned pp = atomicAdd(&s_cnt, 1u); s_list[pp] = a; }
                    else if (k2 == B2) {
                        unsigned c = atomicAdd(&s_ccnt, 1u);
                        if (c < 128u) candi[c] = a;
                    }
                }
            }
        }
    }
    __syncthreads();

    // ---- rank boundary candidates by exact (d, idx), take needN smallest
    int needN = (mode == 0) ? 0 : ((mode == 1) ? sNeed : sNeed2);
    unsigned C = s_ccnt; if (C > 128u) C = 128u;
    if (tid < (int)C) {
        int a = candi[tid];
        float d2 = dist2(pos[a * 3], pos[a * 3 + 1], pos[a * 3 + 2], cx, cy, cz);
        candd[tid] = sqrtf(d2 + 1e-12f);
    }
    __syncthreads();
    if (tid < (int)C) {
        float di = candd[tid]; int ii = candi[tid];
        int rank = 0;
        for (unsigned j = 0; j < C; ++j) {
            float dj = candd[j]; int ij = candi[j];
            if (dj < di || (dj == di && ij < ii)) ++rank;
        }
        if (rank < needN) { unsigned pp = atomicAdd(&s_cnt, 1u); s_list[pp] = ii; }
    }
    __syncthreads();
    if (tid < K_) nbr[r * K_ + tid] = (tid < (int)s_cnt) ? s_list[tid] : -1;
}

// ---------------------------------------------------------------- env: MFMA point-MLP + masked maxpool + env@W2
__global__ __launch_bounds__(256) void k_env(
    const float* __restrict__ pos, const int* __restrict__ atom_name,
    const int* __restrict__ ca_idx, const int* __restrict__ nbr,
    const float* __restrict__ emb, const float* __restrict__ Wxyz,
    const unsigned short* __restrict__ W1t,   // [128][64] bf16
    const float* __restrict__ b1,
    const float* __restrict__ W2, const float* __restrict__ b2,
    float* __restrict__ outZ1)
{
    __shared__ __align__(16) float pts[48 * 68];            // padded rows (272B)
    __shared__ __align__(16) unsigned short W1s[128 * 72];  // padded rows (144B)
    __shared__ float env128[128];
    __shared__ float sWxyz[192];
    __shared__ float s_d[48][3];
    __shared__ int s_a[48];
    __shared__ int s_an[48];

    int tid = threadIdx.x, r = blockIdx.x;

    // stage W1t into padded LDS rows
    for (int c = tid; c < 1024; c += 256)
        *(uint4*)((char*)W1s + (c >> 3) * 144 + (c & 7) * 16) = ((const uint4*)W1t)[c];
    if (tid < 192) sWxyz[tid] = Wxyz[tid];

    int ca = ca_idx[r];
    float cx = pos[ca * 3 + 0], cy = pos[ca * 3 + 1], cz = pos[ca * 3 + 2];
    if (tid < K_) {
        int a = nbr[r * K_ + tid];
        s_a[tid] = a;
        if (a >= 0) {
            s_d[tid][0] = pos[a * 3 + 0] - cx;
            s_d[tid][1] = pos[a * 3 + 1] - cy;
            s_d[tid][2] = pos[a * 3 + 2] - cz;
            s_an[tid] = atom_name[a];
        } else {
            s_d[tid][0] = 0.f; s_d[tid][1] = 0.f; s_d[tid][2] = 0.f;
            s_an[tid] = 0;
        }
    }
    __syncthreads();

    // build pts f32 [48][64] (padded)
    for (int idx = tid; idx < K_ * 64; idx += 256) {
        int row = idx >> 6, k = idx & 63;
        int a = s_a[row];
        float v = 0.f;
        if (a >= 0) {
            v = emb[s_an[row] * 64 + k]
              + s_d[row][0] * sWxyz[k] + s_d[row][1] * sWxyz[64 + k]
              + s_d[row][2] * sWxyz[128 + k];
        }
        pts[row * 68 + k] = v;
    }
    __syncthreads();

    // MFMA: wave w covers output cols 32w..32w+31 (n-tiles 2w, 2w+1), all 48 rows
    int w = tid >> 6, l = tid & 63;
    int fr = l & 15, fo = l >> 4;
    f32x4v acc[3][2];
#pragma unroll
    for (int m = 0; m < 3; ++m)
#pragma unroll
        for (int n = 0; n < 2; ++n) acc[m][n] = (f32x4v){0.f, 0.f, 0.f, 0.f};

#pragma unroll
    for (int ks = 0; ks < 2; ++ks) {
        bfrag8 af[3], bf[2];
#pragma unroll
        for (int m = 0; m < 3; ++m) {
            int row = 16 * m + fr;
            const char* base = (const char*)pts + row * 272 + ks * 128 + fo * 32;
            float4 v0 = *(const float4*)base;
            float4 v1 = *(const float4*)(base + 16);
            bfrag8 t;
            t[0] = (short)bf16rne(v0.x); t[1] = (short)bf16rne(v0.y);
            t[2] = (short)bf16rne(v0.z); t[3] = (short)bf16rne(v0.w);
            t[4] = (short)bf16rne(v1.x); t[5] = (short)bf16rne(v1.y);
            t[6] = (short)bf16rne(v1.z); t[7] = (short)bf16rne(v1.w);
            af[m] = t;
        }
#pragma unroll
        for (int n = 0; n < 2; ++n) {
            int wrow = (2 * w + n) * 16 + fr;
            bf[n] = *(const bfrag8*)((const char*)W1s + wrow * 144 + ks * 64 + fo * 16);
        }
#pragma unroll
        for (int m = 0; m < 3; ++m)
#pragma unroll
            for (int n = 0; n < 2; ++n)
                acc[m][n] = __builtin_amdgcn_mfma_f32_16x16x32_bf16(af[m], bf[n], acc[m][n], 0, 0, 0);
    }

    // bias + relu + masked maxpool (D: col=l&15, row=(l>>4)*4+i)
#pragma unroll
    for (int n = 0; n < 2; ++n) {
        int col = 32 * w + n * 16 + fr;
        float bv = b1[col];
        float m = -1e30f;
#pragma unroll
        for (int mt = 0; mt < 3; ++mt) {
#pragma unroll
            for (int i = 0; i < 4; ++i) {
                int row = 16 * mt + fo * 4 + i;
                if (s_a[row] >= 0) m = fmaxf(m, fmaxf(acc[mt][n][i] + bv, 0.f));
            }
        }
        m = fmaxf(m, __shfl_xor(m, 16));
        m = fmaxf(m, __shfl_xor(m, 32));
        if (fo == 0 && (l & 48) == 0) env128[col] = m;
    }
    __syncthreads();

    // env256 = relu(env128 @ W2 + b2)
    {
        float s = b2[tid];
        for (int i = 0; i < 128; ++i) s += env128[i] * W2[i * 256 + tid];
        outZ1[(size_t)r * 768 + 512 + tid] = fmaxf(s, 0.f);
    }
}

// ---------------------------------------------------------------- bf16 MFMA GEMM (+optional fused BN-input / column stats)
template<bool RELU_OUT, bool BN_A, bool STATS>
__global__ __launch_bounds__(256) void k_mgemm(
    const float* __restrict__ A, int lda, int K,
    const unsigned short* __restrict__ Bt,   // [512][K] bf16
    const float* __restrict__ bias,
    const float* __restrict__ stats, const float* __restrict__ gamma,
    const float* __restrict__ beta,
    float* __restrict__ C, int ldc, float* __restrict__ statsOut)
{
    __shared__ __align__(16) unsigned short As[32 * 32];
    __shared__ __align__(16) unsigned short Bs[64 * 32];
    __shared__ float bnsc[BN_A ? 512 : 1];
    __shared__ float bnsh[BN_A ? 512 : 1];

    int tid = threadIdx.x;
    int m0 = blockIdx.y * 32, n0 = blockIdx.x * 64;

    if (BN_A) {
        for (int i = tid; i < 512; i += 256) {
            float mean = stats[i] * (1.0f / 2048.0f);
            float var = stats[512 + i] * (1.0f / 2048.0f) - mean * mean;
            float inv = 1.0f / sqrtf(var + 1e-5f);
            float scv = gamma[i] * inv;
            bnsc[i] = scv;
            bnsh[i] = beta[i] - mean * scv;
        }
        __syncthreads();
    }

    int w = tid >> 6, l = tid & 63;
    int wm = w >> 1, wn = w & 1;

    int ar = tid >> 3, ac = tid & 7;
    int aslot = ac >> 1, ahalf = ac & 1;
    int abyte = ar * 64 + ((aslot ^ ((ar >> 1) & 3)) << 4) + ahalf * 8;
    int bn_ = tid >> 2, bs_ = tid & 3;
    int bbyte = bn_ * 64 + ((bs_ ^ ((bn_ >> 1) & 3)) << 4);

    int fr = l & 15, fo = l >> 4;
    int arow = 16 * wm + fr;
    int afbyte = arow * 64 + ((fo ^ ((arow >> 1) & 3)) << 4);
    int bcol0 = 32 * wn + fr;
    int bfbyte0 = bcol0 * 64 + ((fo ^ ((bcol0 >> 1) & 3)) << 4);
    int bcol1 = bcol0 + 16;
    int bfbyte1 = bcol1 * 64 + ((fo ^ ((bcol1 >> 1) & 3)) << 4);

    f32x4v acc0 = { 0.f, 0.f, 0.f, 0.f };
    f32x4v acc1 = { 0.f, 0.f, 0.f, 0.f };

    for (int k0 = 0; k0 < K; k0 += 32) {
        float4 av = *(const float4*)(A + (size_t)(m0 + ar) * lda + k0 + ac * 4);
        uint4 bv = *(const uint4*)(Bt + (size_t)(n0 + bn_) * K + k0 + bs_ * 8);
        if (BN_A) {
            int kb = k0 + ac * 4;
            av.x = fmaxf(av.x * bnsc[kb + 0] + bnsh[kb + 0], 0.f);
            av.y = fmaxf(av.y * bnsc[kb + 1] + bnsh[kb + 1], 0.f);
            av.z = fmaxf(av.z * bnsc[kb + 2] + bnsh[kb + 2], 0.f);
            av.w = fmaxf(av.w * bnsc[kb + 3] + bnsh[kb + 3], 0.f);
        }
        unsigned lo = (unsigned)bf16rne(av.x) | ((unsigned)bf16rne(av.y) << 16);
        unsigned hi = (unsigned)bf16rne(av.z) | ((unsigned)bf16rne(av.w) << 16);
        __syncthreads();
        *(uint2*)((char*)As + abyte) = make_uint2(lo, hi);
        *(uint4*)((char*)Bs + bbyte) = bv;
        __syncthreads();

        bfrag8 af = *(const bfrag8*)((const char*)As + afbyte);
        bfrag8 bf0 = *(const bfrag8*)((const char*)Bs + bfbyte0);
        bfrag8 bf1 = *(const bfrag8*)((const char*)Bs + bfbyte1);
        acc0 = __builtin_amdgcn_mfma_f32_16x16x32_bf16(af, bf0, acc0, 0, 0, 0);
        acc1 = __builtin_amdgcn_mfma_f32_16x16x32_bf16(af, bf1, acc1, 0, 0, 0);
    }

    int col0 = n0 + 32 * wn + fr;
    int row = m0 + 16 * wm + fo * 4;
    float bb0 = bias[col0], bb1 = bias[col0 + 16];
    float s0 = 0.f, q0 = 0.f, s1 = 0.f, q1 = 0.f;
#pragma unroll
    for (int i = 0; i < 4; ++i) {
        float v0 = acc0[i] + bb0;
        float v1 = acc1[i] + bb1;
        if (RELU_OUT) { v0 = fmaxf(v0, 0.f); v1 = fmaxf(v1, 0.f); }
        if (STATS) { s0 += v0; q0 += v0 * v0; s1 += v1; q1 += v1 * v1; }
        C[(size_t)(row + i) * ldc + col0] = v0;
        C[(size_t)(row + i) * ldc + col0 + 16] = v1;
    }
    if (STATS) {
        s0 += __shfl_xor(s0, 16); s0 += __shfl_xor(s0, 32);
        q0 += __shfl_xor(q0, 16); q0 += __shfl_xor(q0, 32);
        s1 += __shfl_xor(s1, 16); s1 += __shfl_xor(s1, 32);
        q1 += __shfl_xor(q1, 16); q1 += __shfl_xor(q1, 32);
        if (fo == 0 && (l & 48) == 0) {
            atomicAdd(&statsOut[col0], s0);
            atomicAdd(&statsOut[512 + col0], q0);
            atomicAdd(&statsOut[col0 + 16], s1);
            atomicAdd(&statsOut[512 + col0 + 16], q1);
        }
    }
}

// ---------------------------------------------------------------- launch
extern "C" void kernel_launch(void* const* d_in, const int* in_sizes, int n_in,
                              void* d_out, int out_size, void* d_ws, size_t ws_size,
                              hipStream_t stream)
{
    const float* node   = (const float*)d_in[0];
    const float* pos    = (const float*)d_in[1];
    const int*   aname  = (const int*)d_in[2];
    const int*   caidx  = (const int*)d_in[3];
    const int*   esrc   = (const int*)d_in[4];
    const int*   edst   = (const int*)d_in[5];
    const int*   erel   = (const int*)d_in[6];
    const float* emb    = (const float*)d_in[7];
    const float* Wres   = (const float*)d_in[8];
    const float* bres   = (const float*)d_in[9];
    const float* Wxyz   = (const float*)d_in[10];
    const float* W1     = (const float*)d_in[11];
    const float* b1     = (const float*)d_in[12];
    const float* W2     = (const float*)d_in[13];
    const float* b2     = (const float*)d_in[14];
    const float* Wconv  = (const float*)d_in[15];
    const float* bconv  = (const float*)d_in[16];
    const float* Wself  = (const float*)d_in[17];
    const float* We1    = (const float*)d_in[18];
    const float* be1    = (const float*)d_in[19];
    const float* gamma1 = (const float*)d_in[20];
    const float* beta1  = (const float*)d_in[21];
    const float* We2    = (const float*)d_in[22];
    const float* be2    = (const float*)d_in[23];
    float* out = (float*)d_out;

    char* ws = (char*)d_ws;
    float* resfeat = (float*)(ws + 0);                    // R*64 f32
    float* bufA    = (float*)(ws + 524288);               // R*512 f32 agg|rf
    float* bufZ1   = (float*)(ws + 4718592);              // R*768 f32 hres|env
    float* bufZ2   = (float*)(ws + 11010048);             // R*512 f32 z
    int*   nbr     = (int*)  (ws + 15204352);             // R*48 int
    float* stats   = (float*)(ws + 15597568);             // 1024 f32
    unsigned short* Bt1 = (unsigned short*)(ws + 15601664); // 512x512 bf16
    unsigned short* Bt2 = (unsigned short*)(ws + 16125952); // 512x768 bf16
    unsigned short* Bt3 = (unsigned short*)(ws + 16912384); // 512x512 bf16
    unsigned short* W1t = (unsigned short*)(ws + 17436672); // 128x64 bf16

    hipMemsetAsync(bufA, 0, (size_t)R_ * 512 * 4, stream);
    hipMemsetAsync(stats, 0, 1024 * 4, stream);

    k_prep<<<4128, 256, 0, stream>>>(Wconv, Wself, We1, We2, W1, node, Wres, bres,
                                     Bt1, Bt2, Bt3, W1t, resfeat, bufA);
    k_ball<<<R_, 256, 0, stream>>>(pos, caidx, nbr);
    k_env<<<R_, 256, 0, stream>>>(pos, aname, caidx, nbr, emb, Wxyz, W1t, b1, W2, b2, bufZ1);
    k_edges<<<(size_t)E_ * 64 / 256, 256, 0, stream>>>(esrc, edst, erel, resfeat, bufA);

    dim3 gg(512 / 64, R_ / 32);
    // hres = relu([agg|rf] @ [Wconv;Wself] + bconv) -> bufZ1 cols 0..511
    k_mgemm<true, false, false><<<gg, 256, 0, stream>>>(
        bufA, 512, 512, Bt1, bconv, nullptr, nullptr, nullptr, bufZ1, 768, nullptr);
    // z = [hres|env] @ We1 + be1 -> bufZ2  (+ fused BN column stats)
    k_mgemm<false, false, true><<<gg, 256, 0, stream>>>(
        bufZ1, 768, 768, Bt2, be1, nullptr, nullptr, nullptr, bufZ2, 512, stats);
    // out = relu(BN(z)) @ We2 + be2
    k_mgemm<false, true, false><<<gg, 256, 0, stream>>>(
        bufZ2, 512, 512, Bt3, be2, stats, gamma1, beta1, out, 512, nullptr);
}